// Round 1
// baseline (628.124 us; speedup 1.0000x reference)
//
#include <hip/hip_runtime.h>
#include <hip/hip_bf16.h>

// Hierarchical softmax skip-gram scorer.
// out[b] = prod_l sigmoid(sign[b,l] * dot(logistic[path_idx[b,l]], encoder[v_j[b]]))
// padded levels (sign==0) contribute 1.0. mask == (sign != 0).
//
// v4: deep load pipelining. One wave per batch element, half-wave level split
// (lanes 0-31 even levels, 32-63 odd levels; float4 x 32 lanes = one 512 B row).
// v3 issued row loads in rounds of 4 and then stalled on the dependent
// butterfly+exp chain before the next round => ~3 exposed memory round-trips
// per wave. v4 phases the wave:
//   1) gather ALL per-slot codes c[s] from the lane-parallel metadata regs
//   2) issue ALL logistic row loads back-to-back (fully unrolled, predicated
//      on c!=0; up to MAX_S=16 slots / 32 levels held in registers)
//   3) dot + 5-stage butterfly + sigmoid per slot, consuming loads in order
// => one exposed round-trip. Costs ~64 VGPR for w[] (occupancy 8->4 waves/SIMD)
// but gives ~16 outstanding loads per wave: MLP replaces TLP.

#define D 128
#define MAX_S 16   // slots held in registers; covers L <= 32 (actual L ~ 18)

__global__ __launch_bounds__(256) void hs_prob_kernel(
    const float* __restrict__ encoder,
    const float* __restrict__ logistic,
    const int*   __restrict__ v_j,
    const int*   __restrict__ path_idx,
    const int*   __restrict__ path_sign,
    float*       __restrict__ out,
    int B, int L)
{
    const int gtid = blockIdx.x * blockDim.x + threadIdx.x;
    const int wave = gtid >> 6;       // one wave per batch element
    const int lane = threadIdx.x & 63;
    if (wave >= B) return;
    const int b = wave;

    const int half    = lane >> 5;    // 0 = even levels, 1 = odd levels
    const int sublane = lane & 31;

    // h = encoder[v_j[b]] — float4 per lane, both halves read the same row
    const int vj = v_j[b];                     // wave-uniform
    const float4 h = ((const float4*)(encoder + (long long)vj * D))[sublane];

    // Lane-parallel metadata preload: c = sign * idx. c==0 <=> padded level.
    int c_l = 0;
    if (lane < L)
        c_l = path_sign[(long long)b * L + lane] * path_idx[(long long)b * L + lane];

    const int S = (L + 2) >> 1;       // slots; slot s covers level 2s+half

    // ---- Phase 1: gather this half's per-slot codes (register-only) ----
    // Lanes >= L hold c_l = 0, so in-range shuffles of padded levels give 0.
    int c[MAX_S];
    #pragma unroll
    for (int s = 0; s < MAX_S; ++s) {
        const int lvl = 2 * s + half;            // < 32 < 64, always valid
        const int cv  = __shfl(c_l, lvl, 64);
        c[s] = (s < S) ? cv : 0;
    }

    // ---- Phase 2: issue ALL row loads (half-wave-uniform predication) ----
    float4 w[MAX_S];
    #pragma unroll
    for (int s = 0; s < MAX_S; ++s) {
        if (c[s]) {
            const int ix = c[s] < 0 ? -c[s] : c[s];
            w[s] = ((const float4*)(logistic + (long long)ix * D))[sublane];
        }
    }

    // ---- Phase 3: dot + butterfly + sigmoid, consuming loads in order ----
    float prod = 1.0f;                // per-half partial product
    #pragma unroll
    for (int s = 0; s < MAX_S; ++s) {
        if (c[s]) {
            float p = fmaf(w[s].x, h.x,
                      fmaf(w[s].y, h.y,
                      fmaf(w[s].z, h.z, w[s].w * h.w)));
            #pragma unroll
            for (int off = 16; off; off >>= 1)   // 5-stage, stays in-half
                p += __shfl_xor(p, off, 64);
            const float x = c[s] > 0 ? p : -p;
            prod *= 1.0f / (1.0f + __expf(-x));
        }
    }

    // Generic tail for very deep trees (S > MAX_S) — not hit at L ~ 18.
    for (int s = MAX_S; s < S; ++s) {
        const int cv = __shfl(c_l, 2 * s + half, 64);
        const int ix = cv < 0 ? -cv : cv;
        const float4 wt = ((const float4*)(logistic + (long long)ix * D))[sublane];
        float p = fmaf(wt.x, h.x, fmaf(wt.y, h.y, fmaf(wt.z, h.z, wt.w * h.w)));
        #pragma unroll
        for (int off = 16; off; off >>= 1)
            p += __shfl_xor(p, off, 64);
        const float x = cv > 0 ? p : -p;
        const float f = 1.0f / (1.0f + __expf(-x));
        prod *= (cv ? f : 1.0f);
    }

    // combine the two halves' partial products
    prod *= __shfl_xor(prod, 32, 64);

    if (lane == 0) out[b] = prod;
}

extern "C" void kernel_launch(void* const* d_in, const int* in_sizes, int n_in,
                              void* d_out, int out_size, void* d_ws, size_t ws_size,
                              hipStream_t stream) {
    const float* encoder   = (const float*)d_in[0];
    const float* logistic  = (const float*)d_in[1];
    const int*   v_j       = (const int*)d_in[2];
    const int*   path_idx  = (const int*)d_in[3];
    const int*   path_sign = (const int*)d_in[4];
    // d_in[5] = path_mask (bool) — unused: mask == (path_sign != 0)

    const int B = in_sizes[2];
    const int L = in_sizes[3] / B;

    float* out = (float*)d_out;

    const int block = 256;                     // 4 waves per block
    const int grid  = (B * 64 + block - 1) / block;
    hipLaunchKernelGGL(hs_prob_kernel, dim3(grid), dim3(block), 0, stream,
                       encoder, logistic, v_j, path_idx, path_sign, out, B, L);
}